// Round 1
// baseline (241.907 us; speedup 1.0000x reference)
//
#include <hip/hip_runtime.h>
#include <cstddef>

// Problem constants
#define BB 8
#define CC 64
#define OO 64
#define HH 256
#define WW 256
#define MODES 16

// Workspace layout (float offsets)
//  [0)        xbar_w  [B][C][H]      131072
//  [131072)   xbar_h  [B][C][W]      131072
//  [262144)   ft_re   [2][B][C][16]   16384
//  [278528)   ft_im   [2][B][C][16]   16384
//  [294912)   box_re  [2][B][O][16]   16384
//  [311296)   box_im  [2][B][O][16]   16384
//  [327680)   g       [2][B][O][256] 262144
//  total 589824 floats = 2.36 MB
#define WS_XBAR   0
#define WS_FTRE   262144
#define WS_FTIM   278528
#define WS_BOXRE  294912
#define WS_BOXIM  311296
#define WS_G      327680

// ---------------------------------------------------------------------------
// K1: per-(b,c) slice, compute mean over W (-> xbar_w[b,c,h]) and mean over H
// (-> xbar_h[b,c,w]) in a single pass over x.
// grid = B*C blocks, 256 threads (4 waves); wave w handles rows [64w,64w+64).
__global__ void k_means(const float* __restrict__ x,
                        float* __restrict__ xbw,   // [B*C][256]
                        float* __restrict__ xbh) { // [B*C][256]
    const int bc   = blockIdx.x;                 // 0..511
    const int t    = threadIdx.x;                // 0..255
    const int wave = t >> 6;
    const int lane = t & 63;
    const float* xs = x + (size_t)bc * (HH * WW);

    __shared__ float colsum[4][WW];

    float c0 = 0.f, c1 = 0.f, c2 = 0.f, c3 = 0.f;
    const int h0 = wave * 64;
    for (int h = h0; h < h0 + 64; ++h) {
        const float4 v = *reinterpret_cast<const float4*>(xs + (size_t)h * WW + lane * 4);
        c0 += v.x; c1 += v.y; c2 += v.z; c3 += v.w;
        float rs = (v.x + v.y) + (v.z + v.w);
        #pragma unroll
        for (int off = 32; off > 0; off >>= 1) rs += __shfl_xor(rs, off, 64);
        if (lane == 0) xbw[bc * HH + h] = rs * (1.0f / WW);
    }
    colsum[wave][lane * 4 + 0] = c0;
    colsum[wave][lane * 4 + 1] = c1;
    colsum[wave][lane * 4 + 2] = c2;
    colsum[wave][lane * 4 + 3] = c3;
    __syncthreads();
    const float s = (colsum[0][t] + colsum[1][t]) + (colsum[2][t] + colsum[3][t]);
    xbh[bc * WW + t] = s * (1.0f / HH);
}

// ---------------------------------------------------------------------------
// K2a: 16-mode DFT (ortho forward) of each 256-vector of means.
// grid = 2*B*C blocks (xbar_w then xbar_h are contiguous), 256 threads.
// thread t: mode k = t>>4, sub-chunk j = t&15 sums 16 samples, then a 16-lane
// shfl_xor reduction.
__global__ void k_dft(const float* __restrict__ xbar,  // [1024][256]
                      float* __restrict__ ftre,        // [1024][16]
                      float* __restrict__ ftim) {
    const int blk = blockIdx.x;      // 0..1023
    const int t = threadIdx.x;
    __shared__ float vs[256];
    vs[t] = xbar[(size_t)blk * 256 + t];
    __syncthreads();

    const int k = t >> 4;
    const int j = t & 15;
    float sre = 0.f, sim = 0.f;
    const float wk = 6.2831853071795864769f * (float)k / 256.0f;
    #pragma unroll
    for (int i = 0; i < 16; ++i) {
        const int h = j * 16 + i;
        float s, c;
        sincosf(wk * (float)h, &s, &c);
        sre += vs[h] * c;
        sim -= vs[h] * s;
    }
    #pragma unroll
    for (int m = 1; m < 16; m <<= 1) {
        sre += __shfl_xor(sre, m, 64);
        sim += __shfl_xor(sim, m, 64);
    }
    if (j == 0) {
        ftre[blk * MODES + k] = sre * (1.0f / 16.0f);   // 1/sqrt(256)
        ftim[blk * MODES + k] = sim * (1.0f / 16.0f);
    }
}

// ---------------------------------------------------------------------------
// K2b: channel mix in mode space: box[br,b,o,k] = sum_c ft[br,b,c,k]*w[c,o,k]
// grid = 2*B blocks, 256 threads; each thread does 4 (o,k) pairs.
__global__ void k_modemix(const float* __restrict__ ftre,
                          const float* __restrict__ ftim,
                          const float* __restrict__ wxr, const float* __restrict__ wxi,
                          const float* __restrict__ wyr, const float* __restrict__ wyi,
                          float* __restrict__ boxre, float* __restrict__ boxim) {
    const int blk = blockIdx.x;      // 0..15 : br = blk>>3, b = blk&7
    const int br  = blk >> 3;
    const int t   = threadIdx.x;

    const float* wr = br ? wyr : wxr;
    const float* wi = br ? wyi : wxi;

    __shared__ float fr[CC * MODES];   // [c][k]
    __shared__ float fi[CC * MODES];
    #pragma unroll
    for (int i = 0; i < 4; ++i) {
        fr[t + i * 256] = ftre[blk * (CC * MODES) + t + i * 256];
        fi[t + i * 256] = ftim[blk * (CC * MODES) + t + i * 256];
    }
    __syncthreads();

    const int k  = t & 15;
    const int ob = t >> 4;           // 0..15
    #pragma unroll
    for (int p = 0; p < 4; ++p) {
        const int o = ob + p * 16;
        float are = 0.f, aim = 0.f;
        for (int c = 0; c < CC; ++c) {
            const float frv = fr[c * MODES + k];
            const float fiv = fi[c * MODES + k];
            const float wrv = wr[(c * OO + o) * MODES + k];
            const float wiv = wi[(c * OO + o) * MODES + k];
            are += frv * wrv - fiv * wiv;
            aim += frv * wiv + fiv * wrv;
        }
        boxre[blk * (OO * MODES) + o * MODES + k] = are;
        boxim[blk * (OO * MODES) + o * MODES + k] = aim;
    }
}

// ---------------------------------------------------------------------------
// K2c: inverse synthesis (ortho irfft of 16-mode spectrum, broadcast axis
// dropped): g[br,b,o,p] = (1/16)*(re0 + sum_{k>=1} 2*(re_k cos - im_k sin))
// grid = 2*B*O blocks, 256 threads (p).
__global__ void k_synth(const float* __restrict__ boxre,
                        const float* __restrict__ boxim,
                        float* __restrict__ g) {
    const int blk = blockIdx.x;      // 0..1023 = (br*B+b)*64 + o
    const int t   = threadIdx.x;     // position h or w
    __shared__ float bre[MODES], bim[MODES];
    if (t < MODES)        bre[t] = boxre[(blk >> 6) * (OO * MODES) + (blk & 63) * MODES + t];
    else if (t < 2*MODES) bim[t - MODES] = boxim[(blk >> 6) * (OO * MODES) + (blk & 63) * MODES + (t - MODES)];
    __syncthreads();

    float acc = bre[0];
    const float wt = 6.2831853071795864769f * (float)t / 256.0f;
    #pragma unroll
    for (int k = 1; k < MODES; ++k) {
        float s, c;
        sincosf(wt * (float)k, &s, &c);
        acc += 2.0f * (bre[k] * c - bim[k] * s);
    }
    g[(size_t)blk * 256 + t] = acc * (1.0f / 16.0f);
}

// ---------------------------------------------------------------------------
// K3: fused epilogue: out[b,o,h,w] = sum_c x[b,c,h,w]*mix_w[o,c] + mix_b[o]
//                                    + gx[b,o,h] + gy[b,o,w]
// grid = B*H blocks (one W-row each), 256 threads = w.
__global__ void k_final(const float* __restrict__ x,
                        const float* __restrict__ mw,  // [O][C]
                        const float* __restrict__ mb,  // [O]
                        const float* __restrict__ g,   // [2][B][O][256]
                        float* __restrict__ out) {
    const int blk = blockIdx.x;      // b*256 + h
    const int b = blk >> 8;
    const int h = blk & 255;
    const int w = threadIdx.x;

    const float* gx = g;                      // [B][O][256] indexed by h
    const float* gy = g + BB * OO * 256;      // [B][O][256] indexed by w

    float xr[CC];
    const float* xp = x + ((size_t)b * CC * HH + h) * WW + w;
    #pragma unroll
    for (int c = 0; c < CC; ++c) xr[c] = xp[(size_t)c * (HH * WW)];

    float* op = out + ((size_t)b * OO * HH + h) * WW + w;
    for (int o = 0; o < OO; ++o) {
        float acc = mb[o] + gx[(b * OO + o) * 256 + h] + gy[(b * OO + o) * 256 + w];
        #pragma unroll
        for (int c = 0; c < CC; ++c) acc += xr[c] * mw[o * CC + c];
        op[(size_t)o * (HH * WW)] = acc;
    }
}

// ---------------------------------------------------------------------------
extern "C" void kernel_launch(void* const* d_in, const int* in_sizes, int n_in,
                              void* d_out, int out_size, void* d_ws, size_t ws_size,
                              hipStream_t stream) {
    const float* x    = (const float*)d_in[0];
    const float* wxr  = (const float*)d_in[1];
    const float* wxi  = (const float*)d_in[2];
    const float* wyr  = (const float*)d_in[3];
    const float* wyi  = (const float*)d_in[4];
    const float* mixw = (const float*)d_in[5];
    const float* mixb = (const float*)d_in[6];
    float* out = (float*)d_out;
    float* ws  = (float*)d_ws;

    float* xbar  = ws + WS_XBAR;    // [2][B][C][256] (xbar_w then xbar_h)
    float* ftre  = ws + WS_FTRE;
    float* ftim  = ws + WS_FTIM;
    float* boxre = ws + WS_BOXRE;
    float* boxim = ws + WS_BOXIM;
    float* g     = ws + WS_G;

    k_means<<<BB * CC, 256, 0, stream>>>(x, xbar, xbar + BB * CC * HH);
    k_dft<<<2 * BB * CC, 256, 0, stream>>>(xbar, ftre, ftim);
    k_modemix<<<2 * BB, 256, 0, stream>>>(ftre, ftim, wxr, wxi, wyr, wyi, boxre, boxim);
    k_synth<<<2 * BB * OO, 256, 0, stream>>>(boxre, boxim, g);
    k_final<<<BB * HH, 256, 0, stream>>>(x, mixw, mixb, g, out);
}

// Round 2
// 140.330 us; speedup vs baseline: 1.7238x; 1.7238x over previous
//
#include <hip/hip_runtime.h>
#include <cstddef>

// Problem constants
#define BB 8
#define CC 64
#define OO 64
#define HH 256
#define WW 256
#define MODES 16

// Workspace layout (float offsets)
#define WS_XBAR   0
#define WS_FTRE   262144
#define WS_FTIM   278528
#define WS_BOXRE  294912
#define WS_BOXIM  311296
#define WS_G      327680

typedef __attribute__((ext_vector_type(8)))  short short8v;
typedef __attribute__((ext_vector_type(16))) float f32x16;

__device__ __forceinline__ unsigned short f2bf(float f) {
    unsigned u = __builtin_bit_cast(unsigned, f);
    u += 0x7fffu + ((u >> 16) & 1u);           // RNE
    return (unsigned short)(u >> 16);
}
__device__ __forceinline__ float bf2f(unsigned short s) {
    unsigned u = ((unsigned)s) << 16;
    return __builtin_bit_cast(float, u);
}

// ---------------------------------------------------------------------------
// K1: per-(b,c) slice, mean over W (-> xbar_w[b,c,h]) and mean over H
// (-> xbar_h[b,c,w]) in one pass.
__global__ void k_means(const float* __restrict__ x,
                        float* __restrict__ xbw,   // [B*C][256]
                        float* __restrict__ xbh) { // [B*C][256]
    const int bc   = blockIdx.x;
    const int t    = threadIdx.x;
    const int wave = t >> 6;
    const int lane = t & 63;
    const float* xs = x + (size_t)bc * (HH * WW);

    __shared__ float colsum[4][WW];

    float c0 = 0.f, c1 = 0.f, c2 = 0.f, c3 = 0.f;
    const int h0 = wave * 64;
    for (int h = h0; h < h0 + 64; ++h) {
        const float4 v = *reinterpret_cast<const float4*>(xs + (size_t)h * WW + lane * 4);
        c0 += v.x; c1 += v.y; c2 += v.z; c3 += v.w;
        float rs = (v.x + v.y) + (v.z + v.w);
        #pragma unroll
        for (int off = 32; off > 0; off >>= 1) rs += __shfl_xor(rs, off, 64);
        if (lane == 0) xbw[bc * HH + h] = rs * (1.0f / WW);
    }
    colsum[wave][lane * 4 + 0] = c0;
    colsum[wave][lane * 4 + 1] = c1;
    colsum[wave][lane * 4 + 2] = c2;
    colsum[wave][lane * 4 + 3] = c3;
    __syncthreads();
    const float s = (colsum[0][t] + colsum[1][t]) + (colsum[2][t] + colsum[3][t]);
    xbh[bc * WW + t] = s * (1.0f / HH);
}

// ---------------------------------------------------------------------------
// K2a: 16-mode ortho DFT of each 256-vector of means.
__global__ void k_dft(const float* __restrict__ xbar,  // [1024][256]
                      float* __restrict__ ftre,        // [1024][16]
                      float* __restrict__ ftim) {
    const int blk = blockIdx.x;
    const int t = threadIdx.x;
    __shared__ float vs[256];
    vs[t] = xbar[(size_t)blk * 256 + t];
    __syncthreads();

    const int k = t >> 4;
    const int j = t & 15;
    float sre = 0.f, sim = 0.f;
    const float wk = 6.2831853071795864769f * (float)k / 256.0f;
    #pragma unroll
    for (int i = 0; i < 16; ++i) {
        const int h = j * 16 + i;
        float s, c;
        sincosf(wk * (float)h, &s, &c);
        sre += vs[h] * c;
        sim -= vs[h] * s;
    }
    #pragma unroll
    for (int m = 1; m < 16; m <<= 1) {
        sre += __shfl_xor(sre, m, 64);
        sim += __shfl_xor(sim, m, 64);
    }
    if (j == 0) {
        ftre[blk * MODES + k] = sre * (1.0f / 16.0f);
        ftim[blk * MODES + k] = sim * (1.0f / 16.0f);
    }
}

// ---------------------------------------------------------------------------
// K2b: channel mix in mode space.
__global__ void k_modemix(const float* __restrict__ ftre,
                          const float* __restrict__ ftim,
                          const float* __restrict__ wxr, const float* __restrict__ wxi,
                          const float* __restrict__ wyr, const float* __restrict__ wyi,
                          float* __restrict__ boxre, float* __restrict__ boxim) {
    const int blk = blockIdx.x;      // 0..15 : br = blk>>3, b = blk&7
    const int br  = blk >> 3;
    const int t   = threadIdx.x;

    const float* wr = br ? wyr : wxr;
    const float* wi = br ? wyi : wxi;

    __shared__ float fr[CC * MODES];
    __shared__ float fi[CC * MODES];
    #pragma unroll
    for (int i = 0; i < 4; ++i) {
        fr[t + i * 256] = ftre[blk * (CC * MODES) + t + i * 256];
        fi[t + i * 256] = ftim[blk * (CC * MODES) + t + i * 256];
    }
    __syncthreads();

    const int k  = t & 15;
    const int ob = t >> 4;
    #pragma unroll
    for (int p = 0; p < 4; ++p) {
        const int o = ob + p * 16;
        float are = 0.f, aim = 0.f;
        for (int c = 0; c < CC; ++c) {
            const float frv = fr[c * MODES + k];
            const float fiv = fi[c * MODES + k];
            const float wrv = wr[(c * OO + o) * MODES + k];
            const float wiv = wi[(c * OO + o) * MODES + k];
            are += frv * wrv - fiv * wiv;
            aim += frv * wiv + fiv * wrv;
        }
        boxre[blk * (OO * MODES) + o * MODES + k] = are;
        boxim[blk * (OO * MODES) + o * MODES + k] = aim;
    }
}

// ---------------------------------------------------------------------------
// K2c: inverse synthesis; mix_b folded into the gx (br==0) part.
__global__ void k_synth(const float* __restrict__ boxre,
                        const float* __restrict__ boxim,
                        const float* __restrict__ mb,
                        float* __restrict__ g) {
    const int blk = blockIdx.x;      // (br*B+b)*64 + o
    const int t   = threadIdx.x;
    __shared__ float bre[MODES], bim[MODES];
    if (t < MODES)        bre[t] = boxre[(blk >> 6) * (OO * MODES) + (blk & 63) * MODES + t];
    else if (t < 2*MODES) bim[t - MODES] = boxim[(blk >> 6) * (OO * MODES) + (blk & 63) * MODES + (t - MODES)];
    __syncthreads();

    float acc = bre[0];
    const float wt = 6.2831853071795864769f * (float)t / 256.0f;
    #pragma unroll
    for (int k = 1; k < MODES; ++k) {
        float s, c;
        sincosf(wt * (float)k, &s, &c);
        acc += 2.0f * (bre[k] * c - bim[k] * s);
    }
    float v = acc * (1.0f / 16.0f);
    if (blk < BB * OO) v += mb[blk & 63];   // fold bias into gx
    g[(size_t)blk * 256 + t] = v;
}

// ---------------------------------------------------------------------------
// K3: MFMA epilogue GEMM.
// out[b,o,h,w] = sum_c mw[o,c] x[b,c,h,w] + gx'[b,o,h] + gy[b,o,w]
// (gx' already contains mix_b.)
// A = mw (M=64 o, K=64 c) split bf16 hi/lo; B = x (K=64 c, N=pixels) split.
// v_mfma_f32_32x32x16_bf16; 3 MFMAs per k-block (xh*wh + xl*wh + xh*wl).
// grid = B * 2(o-tiles) * 128(strips); 256 threads = 4 waves; each wave does
// four 32-pixel tiles (tiles never cross a row, so h is uniform per tile).
__global__ void __launch_bounds__(256) k_final_mfma(
        const float* __restrict__ x,
        const float* __restrict__ mw,   // [O][C]
        const float* __restrict__ g,    // [2][B][O][256]
        float* __restrict__ out) {
    const int tid  = threadIdx.x;
    const int lane = tid & 63;
    const int wv   = tid >> 6;
    const int blk  = blockIdx.x;
    const int strip = blk & 127;
    const int ot    = (blk >> 7) & 1;
    const int b     = blk >> 8;
    const int nlo   = lane & 31;
    const int half  = lane >> 5;

    const float* gx = g + (size_t)(b * OO) * 256;
    const float* gy = g + (size_t)BB * OO * 256 + (size_t)(b * OO) * 256;

    // A fragments (weights), loaded once: o = ot*32+nlo, c = kb*16 + 8*half + i
    short8v wh[4], wl[4];
    {
        const int o = ot * 32 + nlo;
        const float* wrow = mw + o * CC + 8 * half;
        #pragma unroll
        for (int kb = 0; kb < 4; ++kb) {
            #pragma unroll
            for (int i = 0; i < 8; ++i) {
                float v = wrow[kb * 16 + i];
                unsigned short h = f2bf(v);
                wh[kb][i] = (short)h;
                wl[kb][i] = (short)f2bf(v - bf2f(h));
            }
        }
    }

    const float* xb = x + (size_t)b * CC * (HH * WW);
    float*       ob = out + (size_t)b * OO * (HH * WW);

    for (int it = 0; it < 4; ++it) {
        const int p0 = strip * 512 + it * 128 + wv * 32;
        const int h  = p0 >> 8;
        const int w0 = p0 & 255;

        // gather B: x[c][p0 + nlo], c = kb*16 + 8*half + i (128B segments)
        float xv[32];
        #pragma unroll
        for (int kb = 0; kb < 4; ++kb)
            #pragma unroll
            for (int i = 0; i < 8; ++i) {
                const int c = kb * 16 + 8 * half + i;
                xv[kb * 8 + i] = xb[(size_t)c * (HH * WW) + p0 + nlo];
            }

        f32x16 acc;
        #pragma unroll
        for (int i = 0; i < 16; ++i) acc[i] = 0.f;

        #pragma unroll
        for (int kb = 0; kb < 4; ++kb) {
            short8v xh, xl;
            #pragma unroll
            for (int i = 0; i < 8; ++i) {
                const float v = xv[kb * 8 + i];
                const unsigned short hh = f2bf(v);
                xh[i] = (short)hh;
                xl[i] = (short)f2bf(v - bf2f(hh));
            }
            acc = __builtin_amdgcn_mfma_f32_32x32x16_bf16(wh[kb], xh, acc, 0, 0, 0);
            acc = __builtin_amdgcn_mfma_f32_32x32x16_bf16(wl[kb], xh, acc, 0, 0, 0);
            acc = __builtin_amdgcn_mfma_f32_32x32x16_bf16(wh[kb], xl, acc, 0, 0, 0);
        }

        // epilogue + store: row(o_local) = (r&3) + 8*(r>>2) + 4*half (verified C/D map)
        #pragma unroll
        for (int r = 0; r < 16; ++r) {
            const int o = ot * 32 + (r & 3) + 8 * (r >> 2) + 4 * half;
            const float v = acc[r] + gx[o * 256 + h] + gy[o * 256 + w0 + nlo];
            ob[(size_t)o * (HH * WW) + p0 + nlo] = v;
        }
    }
}

// ---------------------------------------------------------------------------
extern "C" void kernel_launch(void* const* d_in, const int* in_sizes, int n_in,
                              void* d_out, int out_size, void* d_ws, size_t ws_size,
                              hipStream_t stream) {
    const float* x    = (const float*)d_in[0];
    const float* wxr  = (const float*)d_in[1];
    const float* wxi  = (const float*)d_in[2];
    const float* wyr  = (const float*)d_in[3];
    const float* wyi  = (const float*)d_in[4];
    const float* mixw = (const float*)d_in[5];
    const float* mixb = (const float*)d_in[6];
    float* out = (float*)d_out;
    float* ws  = (float*)d_ws;

    float* xbar  = ws + WS_XBAR;
    float* ftre  = ws + WS_FTRE;
    float* ftim  = ws + WS_FTIM;
    float* boxre = ws + WS_BOXRE;
    float* boxim = ws + WS_BOXIM;
    float* g     = ws + WS_G;

    k_means<<<BB * CC, 256, 0, stream>>>(x, xbar, xbar + BB * CC * HH);
    k_dft<<<2 * BB * CC, 256, 0, stream>>>(xbar, ftre, ftim);
    k_modemix<<<2 * BB, 256, 0, stream>>>(ftre, ftim, wxr, wxi, wyr, wyi, boxre, boxim);
    k_synth<<<2 * BB * OO, 256, 0, stream>>>(boxre, boxim, mixb, g);
    k_final_mfma<<<BB * 2 * 128, 256, 0, stream>>>(x, mixw, g, out);
}